// Round 10
// baseline (1221.158 us; speedup 1.0000x reference)
//
#include <hip/hip_runtime.h>
#include <hip/hip_bf16.h>
#include <hip/hip_fp8.h>

// Problem constants (MoCo): b=256, nc=5 -> M=1280 rows
#define M_     1280
#define DIM    128
#define DMLP   2048
#define KQ     65536
#define NCOLS  65537ull   // 1 + KQ logits columns
#define NTOPK  5
#define NCHUNK 512        // KQ / 128 (one chunk per gemm2 block)
#define NBLK1  512        // KQ / 128 (gemm1 N-tiles, lse partials)
#define NTK    32         // DMLP / 64 K-tiles for gemm2
#define INV_T  14.285714285714286f   // 1/0.07

typedef __attribute__((ext_vector_type(8))) short bf16x8;  // 8 bf16 (4 VGPRs)
typedef __attribute__((ext_vector_type(4))) float f32x4;   // MFMA accum
typedef __attribute__((ext_vector_type(2))) long longx2;   // 16B fragment pair

static __device__ __forceinline__ unsigned short f2bf(float x){
  union { __hip_bfloat16 h; unsigned short u; } cv;
  cv.h = __float2bfloat16(x);
  return cv.u;
}

static __device__ __forceinline__ unsigned char f2f8(float x){
  __hip_fp8_e4m3 h(x);                 // OCP e4m3 on gfx950
  return (unsigned char)h.__x;
}

// async global->LDS, 16B per lane (m97: the 1.69x step)
#define GLDS16(gp, lp) __builtin_amdgcn_global_load_lds( \
    (const __attribute__((address_space(1))) void*)(gp), \
    (__attribute__((address_space(3))) void*)(lp), 16, 0, 0)

#define BAR()   asm volatile("s_barrier" ::: "memory")
#define VMW(n)  asm volatile("s_waitcnt vmcnt(" #n ")" ::: "memory")

// ---------- transpose + fp32->bf16 convert: in [R][C] f32 -> out [C][R] bf16
__global__ __launch_bounds__(256) void transpose_bf16(
    const float* __restrict__ in, unsigned short* __restrict__ out, int R, int C){
  __shared__ float tile[64][65];             // +1 pad: no bank conflicts
  const int c0 = blockIdx.x * 64, r0 = blockIdx.y * 64;
  const int t = threadIdx.x;
  #pragma unroll
  for (int i = 0; i < 4; ++i){
    int lin = t + i * 256;                   // 0..1023, one float4 each
    int rr = lin >> 4;
    int cc = (lin & 15) * 4;
    const float4 v = *(const float4*)(in + (size_t)(r0 + rr) * C + c0 + cc);
    tile[rr][cc + 0] = v.x; tile[rr][cc + 1] = v.y;
    tile[rr][cc + 2] = v.z; tile[rr][cc + 3] = v.w;
  }
  __syncthreads();
  #pragma unroll
  for (int i = 0; i < 4; ++i){
    int lin = t + i * 256;
    int oc  = lin >> 4;                      // out row (original col)
    int orr = (lin & 15) * 4;                // out col group (original rows)
    ushort4 u;
    u.x = f2bf(tile[orr + 0][oc]); u.y = f2bf(tile[orr + 1][oc]);
    u.z = f2bf(tile[orr + 2][oc]); u.w = f2bf(tile[orr + 3][oc]);
    *(ushort4*)(out + (size_t)(c0 + oc) * R + r0 + orr) = u;
  }
}

// ---------- transpose + fp32->fp8(e4m3), k-interleaved rows, 16B stores:
// within each 64B k-block, byte position = quad*16 + slice*8 + sub where
// k_local = slice*32 + quad*8 + sub. One thread assembles one 16B granule
// (both slices of its quad) -> single ulonglong2 store, fully coalesced.
__global__ __launch_bounds__(256) void transpose_fp8(
    const float* __restrict__ in, unsigned char* __restrict__ out, int R, int C){
  __shared__ float tile[64][65];
  const int c0 = blockIdx.x * 64, r0 = blockIdx.y * 64;
  const int t = threadIdx.x;
  #pragma unroll
  for (int i = 0; i < 4; ++i){
    int lin = t + i * 256;
    int rr = lin >> 4;
    int cc = (lin & 15) * 4;
    const float4 v = *(const float4*)(in + (size_t)(r0 + rr) * C + c0 + cc);
    tile[rr][cc + 0] = v.x; tile[rr][cc + 1] = v.y;
    tile[rr][cc + 2] = v.z; tile[rr][cc + 3] = v.w;
  }
  __syncthreads();
  {
    const int oc   = t >> 2;                 // 0..63 (original col)
    const int quad = t & 3;                  // 16B granule within the 64B block
    union { unsigned char b[16]; ulonglong2 v; } u;
    #pragma unroll
    for (int b = 0; b < 16; ++b)
      u.b[b] = f2f8(tile[(b >> 3) * 32 + quad * 8 + (b & 7)][oc]);
    *(ulonglong2*)(out + (size_t)(c0 + oc) * R + r0 + quad * 16) = u.v;
  }
}

// ---------- normalize q rows -> bf16 qn; also write l_pos (logits col 0)
__global__ __launch_bounds__(128) void normq_kernel(
    const float* __restrict__ q, const float* __restrict__ k,
    unsigned short* __restrict__ qn, float* __restrict__ outp){
  const int i = blockIdx.x;                  // 0..1279
  const int t = threadIdx.x;                 // 0..127
  const float qv = q[(size_t)i * DIM + t];
  const float kv = k[(size_t)(i / 5) * DIM + t];
  float a = qv * qv, b = kv * kv, d = qv * kv;
  #pragma unroll
  for (int s = 32; s >= 1; s >>= 1){
    a += __shfl_down(a, s, 64);
    b += __shfl_down(b, s, 64);
    d += __shfl_down(d, s, 64);
  }
  __shared__ float red[6];
  if ((t & 63) == 0){ red[(t >> 6) * 3 + 0] = a; red[(t >> 6) * 3 + 1] = b; red[(t >> 6) * 3 + 2] = d; }
  __syncthreads();
  const float qq = red[0] + red[3], kk = red[1] + red[4], qk = red[2] + red[5];
  const float qnorm = fmaxf(sqrtf(qq), 1e-12f);
  qn[(size_t)i * DIM + t] = f2bf(qv / qnorm);
  if (t == 0){
    const float knorm = fmaxf(sqrtf(kk), 1e-12f);
    outp[(size_t)i * NCOLS] = (qk / (qnorm * knorm)) * INV_T;   // l_pos / T
  }
}

// ---------- normalize q_backbone rows -> fp8, same k-interleaved byte order
__global__ __launch_bounds__(256) void normqb_kernel(
    const float* __restrict__ qb, unsigned char* __restrict__ out){
  const int i = blockIdx.x, t = threadIdx.x;
  const float* p = qb + (size_t)i * DMLP;
  float x[8]; float ss = 0.f;
  #pragma unroll
  for (int j = 0; j < 8; ++j){ x[j] = p[t + j * 256]; ss += x[j] * x[j]; }
  #pragma unroll
  for (int s = 32; s >= 1; s >>= 1) ss += __shfl_down(ss, s, 64);
  __shared__ float r4[4];
  if ((t & 63) == 0) r4[t >> 6] = ss;
  __syncthreads();
  const float tot = r4[0] + r4[1] + r4[2] + r4[3];
  const float inv = 1.0f / fmaxf(sqrtf(tot), 1e-12f);
  unsigned char* o = out + (size_t)i * DMLP;
  #pragma unroll
  for (int j = 0; j < 8; ++j){
    const int kx = t + j * 256;
    const int kk = kx & 63;
    const int pos = (kx & ~63) + ((kk >> 3) & 3) * 16 + (kk >> 5) * 8 + (kk & 7);
    o[pos] = f2f8(x[j] * inv);
  }
}

// ---------- top-5 insertion (sorted desc; strict > keeps earliest index on ties)
static __device__ __forceinline__ void tk_insert(float* v, int* ix, float nv, int ni){
  if (nv > v[4]){
    v[4] = nv; ix[4] = ni;
    #pragma unroll
    for (int j = 4; j > 0; --j){
      if (v[j] > v[j - 1]){
        float tv = v[j]; v[j] = v[j - 1]; v[j - 1] = tv;
        int   ti = ix[j]; ix[j] = ix[j - 1]; ix[j - 1] = ti;
      }
    }
  }
}

// ================== FUSED GEMM kernel: role-split blocks so the write-bound
// GEMM1 and the MFMA-bound GEMM2 co-run on each CU (disjoint bottleneck pipes;
// one stream forbids overlap across launches). bid%3==0 -> gemm2 (2560 blocks),
// else -> gemm1 (5120 blocks, 512 threads = 8 waves x 16 rows x 128 cols).
// Both roles: 73.7KB LDS, <=128 regs -> 2 blocks/CU in any mix (16 waves = cap).

#define RDA8(SRC) do { _Pragma("unroll") for (int mf = 0; mf < 4; ++mf) \
    av[mf] = *(const longx2*)((SRC) + (wm * 64 + mf * 16 + lid) * 64 + qsw); } while(0)

#define RDB8(SRC) do { _Pragma("unroll") for (int nf = 0; nf < 4; ++nf) \
    bv[nf] = *(const longx2*)((SRC) + (wn * 64 + nf * 16 + lid) * 64 + qsw); } while(0)

#define MM_NF(nj_) do { \
    _Pragma("unroll") for (int mf = 0; mf < 4; ++mf){ \
      acc[mf][nj_] = __builtin_amdgcn_mfma_f32_16x16x32_fp8_fp8(av[mf].x, bv[nj_].x, acc[mf][nj_], 0, 0, 0); \
      acc[mf][nj_] = __builtin_amdgcn_mfma_f32_16x16x32_fp8_fp8(av[mf].y, bv[nj_].y, acc[mf][nj_], 0, 0, 0); } } while(0)

__global__ __launch_bounds__(512, 4) void gemm_fused(
    const unsigned char* __restrict__ A8, const unsigned char* __restrict__ BT8,
    float* __restrict__ cval, int* __restrict__ cidx,
    const unsigned short* __restrict__ A16, const unsigned short* __restrict__ BT16,
    float* __restrict__ outp, float* __restrict__ pm, float* __restrict__ ps){
  __shared__ __attribute__((aligned(16))) unsigned char smem[73728];

  const int bid  = blockIdx.x;
  const int role = bid % 3;               // 0 -> gemm2; 1,2 -> gemm1
  const int t    = threadIdx.x;           // 0..511
  const int lane = t & 63;
  const int wv   = t >> 6;                // wave 0..7
  const int lid  = lane & 15;
  const int quad = lane >> 4;

  if (role == 0){
    // ---------------- GEMM2 (fp8): 256x128 tile, BK=64, 3-buf 2-ahead ----
    const int wm  = wv >> 1;              // 0..3 (64-row band)
    const int wn  = wv & 1;               // 0..1 (64-col band)
    const int qsw = (quad ^ (lid & 3)) * 16;   // swizzled granule byte offset

    // T1: bijective XCD-chunked remap on role-local id (2560 % 8 == 0).
    // g2id ≡ x (mod 8) -> bid = 3*g2id -> XCD (3x)%8: still one XCD per chunk.
    const int h  = bid / 3;
    const int wg = (h & 7) * 320 + (h >> 3);
    const int bm = wg % 5;                // 5 M-tiles of 256 rows
    const int bn = wg / 5;                // 512 N-tiles of 128 cols
    const int m0 = bm * 256;
    const int n0 = bn * 128;

    // staging source map (inverse swizzle; per-thread constant)
    const int srow = t >> 2;
    const size_t roff = (size_t)srow * DMLP + (size_t)(((t & 3) ^ (srow & 3)) * 16);
    const unsigned char* aB = A8  + (size_t)m0 * DMLP;
    const unsigned char* bB = BT8 + (size_t)n0 * DMLP;

    f32x4 acc[4][4];
    #pragma unroll
    for (int a = 0; a < 4; ++a)
      #pragma unroll
      for (int b = 0; b < 4; ++b)
        acc[a][b] = f32x4{0.f, 0.f, 0.f, 0.f};

    longx2 av[4];    // A fragments, all 4 held (16 VGPR)
    longx2 bv[4];    // B fragments, all 4 held (16 VGPR)

    #define STAGE2(kt_, bi_) do { \
      unsigned char* _a = smem + (bi_) * 24576; \
      const int _kc = (kt_) * 64; \
      GLDS16(aB + roff + _kc, _a + (size_t)t * 16); \
      GLDS16(aB + roff + 128 * DMLP + _kc, _a + (size_t)(512 + t) * 16); \
      GLDS16(bB + roff + _kc, _a + 16384 + (size_t)t * 16); } while(0)

    STAGE2(0, 0);
    STAGE2(1, 1);
    VMW(3);             // kt0's 3 loads landed (kt1's 3 remain)
    BAR();

    for (int kt = 0; kt < NTK; ++kt){
      const int bi = kt % 3;
      unsigned char* curA = smem + bi * 24576;
      unsigned char* curB = curA + 16384;

      RDA8(curA);
      RDB8(curB);

      if (kt + 2 < NTK) STAGE2(kt + 2, (kt + 2) % 3);   // deep prefetch

      __builtin_amdgcn_s_setprio(1);
      MM_NF(0); MM_NF(1); MM_NF(2); MM_NF(3);
      __builtin_amdgcn_s_setprio(0);

      if (kt + 1 < NTK){
        if (kt + 2 < NTK){ VMW(3); } else { VMW(0); }   // kt+1's loads landed
        BAR();
      }
    }

    // ---- fused top-5 via LDS scratch, 2 half-passes of 128 rows ----
    float* scratch = (float*)smem;        // [128][133] f32
    BAR();
    #pragma unroll
    for (int p = 0; p < 2; ++p){
      if ((wm >> 1) == p){
        #pragma unroll
        for (int mf = 0; mf < 4; ++mf)
          #pragma unroll
          for (int nf = 0; nf < 4; ++nf)
            #pragma unroll
            for (int r = 0; r < 4; ++r){
              const int lr = (wm & 1) * 64 + mf * 16 + quad * 4 + r;
              scratch[lr * 133 + wn * 64 + nf * 16 + lid] = acc[mf][nf][r];
            }
      }
      __syncthreads();
      {
        const int lr  = t >> 2;           // 0..127
        const int seg = t & 3;            // 4 threads/row, 32 cols each
        float v[5]; int ix[5];
        #pragma unroll
        for (int j = 0; j < 5; ++j){ v[j] = -3.0e38f; ix[j] = 0; }
        const int cb0 = seg * 32;
        for (int j = 0; j < 32; ++j)
          tk_insert(v, ix, scratch[lr * 133 + cb0 + j], n0 + cb0 + j);
        #pragma unroll
        for (int s = 1; s <= 2; s <<= 1){ // full butterfly
          float pv[5]; int pi[5];
          #pragma unroll
          for (int j = 0; j < 5; ++j){ pv[j] = __shfl_xor(v[j], s, 64); pi[j] = __shfl_xor(ix[j], s, 64); }
          #pragma unroll
          for (int j = 0; j < 5; ++j) tk_insert(v, ix, pv[j], pi[j]);
        }
        if (seg == 0){
          const int rowg = m0 + p * 128 + lr;
          const size_t cb = ((size_t)rowg * NCHUNK + bn) * NTOPK;
          #pragma unroll
          for (int j = 0; j < 5; ++j){ cval[cb + j] = v[j]; cidx[cb + j] = ix[j]; }
        }
      }
      __syncthreads();
    }
  } else {
    // ---------------- GEMM1 (bf16): 128x128 tile, one-shot K=128 ----------
    // 8 waves x 16 rows x 128 cols; stage A 32KB + B 32KB, 1 vmcnt+barrier.
    unsigned short* At = (unsigned short*)smem;   // 4 slices x [128][32]
    unsigned short* Bt = At + 16384;              // 32KB each

    const int h  = (bid / 3) * 2 + (role - 1);    // 0..5119
    const int wg = (h & 7) * 640 + (h >> 3);      // XCD-chunk remap
    const int bm = wg % 10;
    const int bn = wg / 10;
    const int m0 = bm * 128;
    const int n0 = bn * 128;

    f32x4 acc[8];
    #pragma unroll
    for (int nt = 0; nt < 8; ++nt) acc[nt] = f32x4{0.f, 0.f, 0.f, 0.f};

    const int arow = t >> 2;            // staging row (4 granules of 16B/row)
    const int ace  = (t & 3) * 8;       // staging col (elements)

    // one-shot stage: 8 async loads/thread (A 4 + B 4), single seal
    #pragma unroll
    for (int kt = 0; kt < 4; ++kt)
      GLDS16(A16 + (size_t)(m0 + arow) * DIM + kt * 32 + ace,
             At + kt * 4096 + t * 8);
    #pragma unroll
    for (int kt = 0; kt < 4; ++kt)
      GLDS16(BT16 + (size_t)(n0 + arow) * DIM + kt * 32 + ace,
             Bt + kt * 4096 + t * 8);
    VMW(0);
    BAR();

    for (int kt = 0; kt < 4; ++kt){     // no syncs inside
      bf16x8 af, bfr[8];
      af = *(const bf16x8*)(At + kt * 4096 + (wv * 16 + lid) * 32 + quad * 8);
      #pragma unroll
      for (int nt = 0; nt < 8; ++nt)
        bfr[nt] = *(const bf16x8*)(Bt + kt * 4096 + (nt * 16 + lid) * 32 + quad * 8);
      #pragma unroll
      for (int nt = 0; nt < 8; ++nt)
        acc[nt] = __builtin_amdgcn_mfma_f32_16x16x32_bf16(af, bfr[nt], acc[nt], 0, 0, 0);
    }

    // C/D layout (m89-verified): col = lane&15, row = quad*4 + reg
    float mx[4], sm[4];
    #pragma unroll
    for (int r = 0; r < 4; ++r) mx[r] = -3.0e38f;
    #pragma unroll
    for (int nt = 0; nt < 8; ++nt)
      #pragma unroll
      for (int r = 0; r < 4; ++r){
        const int mg = m0 + wv * 16 + quad * 4 + r;
        const int ng = n0 + nt * 16 + lid;
        const float x = acc[nt][r] * INV_T;
        outp[(size_t)mg * NCOLS + 1 + ng] = x;
        mx[r] = fmaxf(mx[r], x);
      }
    #pragma unroll
    for (int r = 0; r < 4; ++r){
      #pragma unroll
      for (int s = 8; s >= 1; s >>= 1)
        mx[r] = fmaxf(mx[r], __shfl_xor(mx[r], s, 64));
      sm[r] = 0.f;
    }
    #pragma unroll
    for (int nt = 0; nt < 8; ++nt)
      #pragma unroll
      for (int r = 0; r < 4; ++r)
        sm[r] += __expf(acc[nt][r] * INV_T - mx[r]);
    #pragma unroll
    for (int r = 0; r < 4; ++r){
      #pragma unroll
      for (int s = 8; s >= 1; s >>= 1)
        sm[r] += __shfl_xor(sm[r], s, 64);
      if (lid == 0){
        const int mg = m0 + wv * 16 + quad * 4 + r;
        pm[(size_t)mg * NBLK1 + bn] = mx[r];
        ps[(size_t)mg * NBLK1 + bn] = sm[r];
      }
    }
  }
}

// ---------- merge 512 chunk top-5 lists per row -> global top-5 indices
__global__ __launch_bounds__(256) void topk_merge(
    const float* __restrict__ cval, const int* __restrict__ cidx, int* __restrict__ knn){
  const int row = blockIdx.x, t = threadIdx.x;
  float v[5]; int ix[5];
  #pragma unroll
  for (int j = 0; j < 5; ++j){ v[j] = -3.0e38f; ix[j] = 0; }
  const size_t base = (size_t)row * (NCHUNK * NTOPK);
  #pragma unroll
  for (int j = 0; j < 10; ++j){                  // 2560 candidates / 256 threads
    const int c = t * 10 + j;
    tk_insert(v, ix, cval[base + c], cidx[base + c]);
  }
  __shared__ float lv[256 * 5];
  __shared__ int   li[256 * 5];
  #pragma unroll
  for (int j = 0; j < 5; ++j){ lv[t * 5 + j] = v[j]; li[t * 5 + j] = ix[j]; }
  __syncthreads();
  if (t < 64){
    float v2[5]; int ix2[5];
    #pragma unroll
    for (int j = 0; j < 5; ++j){ v2[j] = -3.0e38f; ix2[j] = 0; }
    for (int L = 0; L < 4; ++L)
      #pragma unroll
      for (int j = 0; j < 5; ++j)
        tk_insert(v2, ix2, lv[(t * 4 + L) * 5 + j], li[(t * 4 + L) * 5 + j]);
    #pragma unroll
    for (int s = 32; s >= 1; s >>= 1){           // tree merge; lane 0 ends valid
      float pv[5]; int pi[5];
      #pragma unroll
      for (int j = 0; j < 5; ++j){ pv[j] = __shfl_down(v2[j], s, 64); pi[j] = __shfl_down(ix2[j], s, 64); }
      #pragma unroll
      for (int j = 0; j < 5; ++j) tk_insert(v2, ix2, pv[j], pi[j]);
    }
    if (t == 0){
      #pragma unroll
      for (int j = 0; j < 5; ++j) knn[(size_t)row * NTOPK + j] = ix2[j];
    }
  }
}

// ---------- merge per-tile lse partials -> per-row logsumexp
__global__ __launch_bounds__(256) void lse_merge(
    const float* __restrict__ pm, const float* __restrict__ ps,
    float* __restrict__ lse){
  const int row = blockIdx.x, t = threadIdx.x;
  const float* pmr = pm + (size_t)row * NBLK1;
  const float* psr = ps + (size_t)row * NBLK1;
  float m = -1.0e30f, s = 0.f;
  #pragma unroll
  for (int c = 0; c < 2; ++c){               // 512 partials / 256 threads
    const float om = pmr[t + c * 256], os = psr[t + c * 256];
    const float nm = fmaxf(m, om);
    s = s * __expf(m - nm) + os * __expf(om - nm);
    m = nm;
  }
  #pragma unroll
  for (int sh = 32; sh >= 1; sh >>= 1){
    const float om = __shfl_down(m, sh, 64), os = __shfl_down(s, sh, 64);
    const float nm = fmaxf(m, om);
    s = s * __expf(m - nm) + os * __expf(om - nm);
    m = nm;
  }
  __shared__ float sm2[4], ss2[4];
  if ((t & 63) == 0){ sm2[t >> 6] = m; ss2[t >> 6] = s; }
  __syncthreads();
  if (t == 0){
    float M = sm2[0], S = ss2[0];
    #pragma unroll
    for (int w = 1; w < 4; ++w){
      const float nm = fmaxf(M, sm2[w]);
      S = S * __expf(M - nm) + ss2[w] * __expf(sm2[w] - nm);
      M = nm;
    }
    lse[row] = M + __logf(S);
  }
}

// ---------- loss = mean over 6400 of (lse[row] - logit[row][1+idx])
__global__ __launch_bounds__(256) void loss_kernel(
    const float* __restrict__ logits, const float* __restrict__ lse,
    const int* __restrict__ knn, float* __restrict__ loss){
  const int i = blockIdx.x * 256 + threadIdx.x;
  float c = 0.f;
  if (i < M_){
    const float l = lse[i];
    #pragma unroll
    for (int j = 0; j < 5; ++j){
      const int id = knn[(size_t)i * NTOPK + j];
      c += l - logits[(size_t)i * NCOLS + 1 + id];
    }
    c *= (1.0f / 6400.0f);
  }
  #pragma unroll
  for (int s = 32; s >= 1; s >>= 1) c += __shfl_down(c, s, 64);
  if ((threadIdx.x & 63) == 0) atomicAdd(loss, c);
}

extern "C" void kernel_launch(void* const* d_in, const int* in_sizes, int n_in,
                              void* d_out, int out_size, void* d_ws, size_t ws_size,
                              hipStream_t stream){
  const float* q   = (const float*)d_in[0];   // [256,5,128]
  const float* k   = (const float*)d_in[1];   // [256,128]
  const float* qbI = (const float*)d_in[2];   // [256,5,2048]
  const float* que = (const float*)d_in[3];   // [128,65536]
  const float* qbb = (const float*)d_in[4];   // [2048,65536]
  float* out = (float*)d_out;

  unsigned char* w = (unsigned char*)d_ws;
  unsigned short* qn    = (unsigned short*)w; w += (size_t)M_ * DIM  * 2;   // 320 KB
  unsigned char*  qbn8  = (unsigned char*)w;  w += (size_t)M_ * DMLP;      // 2.5 MB
  unsigned short* queT  = (unsigned short*)w; w += (size_t)KQ * DIM  * 2;   // 16 MB
  unsigned char*  qbbT8 = (unsigned char*)w;  w += (size_t)KQ * DMLP;      // 128 MB
  float* cval = (float*)w;                    w += (size_t)M_ * NCHUNK * NTOPK * 4;  // 13 MB
  int*   cidx = (int*)w;                      w += (size_t)M_ * NCHUNK * NTOPK * 4;  // 13 MB
  int*   knn  = (int*)w;                      w += (size_t)M_ * NTOPK * 4;
  float* lseb = (float*)w;                    w += (size_t)M_ * 4;
  float* pm   = (float*)w;                    w += (size_t)M_ * NBLK1 * 4;  // 2.6 MB
  float* ps   = (float*)w;                    w += (size_t)M_ * NBLK1 * 4;  // 2.6 MB

  // labels (1280 int32 zeros) + loss slot, contiguous after logits
  hipMemsetAsync(out + (size_t)M_ * NCOLS, 0, (M_ + 1) * sizeof(float), stream);

  transpose_bf16<<<dim3(KQ / 64, DIM  / 64), 256, 0, stream>>>(que, queT, DIM, KQ);
  transpose_fp8 <<<dim3(KQ / 64, DMLP / 64), 256, 0, stream>>>(qbb, qbbT8, DMLP, KQ);
  normq_kernel <<<M_, 128, 0, stream>>>(q, k, qn, out);
  normqb_kernel<<<M_, 256, 0, stream>>>(qbI, qbn8);
  // fused GEMM1+GEMM2: 7680 blocks, bid%3==0 -> gemm2(2560), else gemm1(5120)
  gemm_fused<<<dim3(7680), 512, 0, stream>>>(qbn8, qbbT8, cval, cidx,
                                             qn, queT, out, pm, ps);
  topk_merge<<<M_, 256, 0, stream>>>(cval, cidx, knn);
  lse_merge<<<M_, 256, 0, stream>>>(pm, ps, lseb);
  loss_kernel<<<(M_ + 255) / 256, 256, 0, stream>>>(out, lseb, knn,
                                                    out + (size_t)M_ * NCOLS + M_);
}

// Round 11
// 1193.844 us; speedup vs baseline: 1.0229x; 1.0229x over previous
//
#include <hip/hip_runtime.h>
#include <hip/hip_bf16.h>
#include <hip/hip_fp8.h>

// Problem constants (MoCo): b=256, nc=5 -> M=1280 rows
#define M_     1280
#define DIM    128
#define DMLP   2048
#define KQ     65536
#define NCOLS  65537ull   // 1 + KQ logits columns
#define NTOPK  5
#define NCHUNK 512        // KQ / 128 (one chunk per gemm2 block)
#define NBLK1  512        // KQ / 128 (gemm1 N-tiles, lse partials)
#define NTK    32         // DMLP / 64 K-tiles for gemm2
#define INV_T  14.285714285714286f   // 1/0.07

typedef __attribute__((ext_vector_type(8))) short bf16x8;  // 8 bf16 (4 VGPRs)
typedef __attribute__((ext_vector_type(4))) float f32x4;   // MFMA accum
typedef __attribute__((ext_vector_type(2))) long longx2;   // 16B fragment pair

static __device__ __forceinline__ unsigned short f2bf(float x){
  union { __hip_bfloat16 h; unsigned short u; } cv;
  cv.h = __float2bfloat16(x);
  return cv.u;
}

static __device__ __forceinline__ unsigned char f2f8(float x){
  __hip_fp8_e4m3 h(x);                 // OCP e4m3 on gfx950
  return (unsigned char)h.__x;
}

// async global->LDS, 16B per lane (m97: the 1.69x step)
#define GLDS16(gp, lp) __builtin_amdgcn_global_load_lds( \
    (const __attribute__((address_space(1))) void*)(gp), \
    (__attribute__((address_space(3))) void*)(lp), 16, 0, 0)

#define BAR()   asm volatile("s_barrier" ::: "memory")
#define VMW(n)  asm volatile("s_waitcnt vmcnt(" #n ")" ::: "memory")

// ---------- transpose + fp32->bf16 convert: in [R][C] f32 -> out [C][R] bf16
__global__ __launch_bounds__(256) void transpose_bf16(
    const float* __restrict__ in, unsigned short* __restrict__ out, int R, int C){
  __shared__ float tile[64][65];             // +1 pad: no bank conflicts
  const int c0 = blockIdx.x * 64, r0 = blockIdx.y * 64;
  const int t = threadIdx.x;
  #pragma unroll
  for (int i = 0; i < 4; ++i){
    int lin = t + i * 256;                   // 0..1023, one float4 each
    int rr = lin >> 4;
    int cc = (lin & 15) * 4;
    const float4 v = *(const float4*)(in + (size_t)(r0 + rr) * C + c0 + cc);
    tile[rr][cc + 0] = v.x; tile[rr][cc + 1] = v.y;
    tile[rr][cc + 2] = v.z; tile[rr][cc + 3] = v.w;
  }
  __syncthreads();
  #pragma unroll
  for (int i = 0; i < 4; ++i){
    int lin = t + i * 256;
    int oc  = lin >> 4;                      // out row (original col)
    int orr = (lin & 15) * 4;                // out col group (original rows)
    ushort4 u;
    u.x = f2bf(tile[orr + 0][oc]); u.y = f2bf(tile[orr + 1][oc]);
    u.z = f2bf(tile[orr + 2][oc]); u.w = f2bf(tile[orr + 3][oc]);
    *(ushort4*)(out + (size_t)(c0 + oc) * R + r0 + orr) = u;
  }
}

// ---------- transpose + fp32->fp8(e4m3), k-interleaved rows, 16B stores:
// within each 64B k-block, byte position = quad*16 + slice*8 + sub where
// k_local = slice*32 + quad*8 + sub. One thread assembles one 16B granule
// (both slices of its quad) -> single ulonglong2 store, fully coalesced.
__global__ __launch_bounds__(256) void transpose_fp8(
    const float* __restrict__ in, unsigned char* __restrict__ out, int R, int C){
  __shared__ float tile[64][65];
  const int c0 = blockIdx.x * 64, r0 = blockIdx.y * 64;
  const int t = threadIdx.x;
  #pragma unroll
  for (int i = 0; i < 4; ++i){
    int lin = t + i * 256;
    int rr = lin >> 4;
    int cc = (lin & 15) * 4;
    const float4 v = *(const float4*)(in + (size_t)(r0 + rr) * C + c0 + cc);
    tile[rr][cc + 0] = v.x; tile[rr][cc + 1] = v.y;
    tile[rr][cc + 2] = v.z; tile[rr][cc + 3] = v.w;
  }
  __syncthreads();
  {
    const int oc   = t >> 2;                 // 0..63 (original col)
    const int quad = t & 3;                  // 16B granule within the 64B block
    union { unsigned char b[16]; ulonglong2 v; } u;
    #pragma unroll
    for (int b = 0; b < 16; ++b)
      u.b[b] = f2f8(tile[(b >> 3) * 32 + quad * 8 + (b & 7)][oc]);
    *(ulonglong2*)(out + (size_t)(c0 + oc) * R + r0 + quad * 16) = u.v;
  }
}

// ---------- normalize q rows -> bf16 qn; also write l_pos (logits col 0)
__global__ __launch_bounds__(128) void normq_kernel(
    const float* __restrict__ q, const float* __restrict__ k,
    unsigned short* __restrict__ qn, float* __restrict__ outp){
  const int i = blockIdx.x;                  // 0..1279
  const int t = threadIdx.x;                 // 0..127
  const float qv = q[(size_t)i * DIM + t];
  const float kv = k[(size_t)(i / 5) * DIM + t];
  float a = qv * qv, b = kv * kv, d = qv * kv;
  #pragma unroll
  for (int s = 32; s >= 1; s >>= 1){
    a += __shfl_down(a, s, 64);
    b += __shfl_down(b, s, 64);
    d += __shfl_down(d, s, 64);
  }
  __shared__ float red[6];
  if ((t & 63) == 0){ red[(t >> 6) * 3 + 0] = a; red[(t >> 6) * 3 + 1] = b; red[(t >> 6) * 3 + 2] = d; }
  __syncthreads();
  const float qq = red[0] + red[3], kk = red[1] + red[4], qk = red[2] + red[5];
  const float qnorm = fmaxf(sqrtf(qq), 1e-12f);
  qn[(size_t)i * DIM + t] = f2bf(qv / qnorm);
  if (t == 0){
    const float knorm = fmaxf(sqrtf(kk), 1e-12f);
    outp[(size_t)i * NCOLS] = (qk / (qnorm * knorm)) * INV_T;   // l_pos / T
  }
}

// ---------- normalize q_backbone rows -> fp8, same k-interleaved byte order
__global__ __launch_bounds__(256) void normqb_kernel(
    const float* __restrict__ qb, unsigned char* __restrict__ out){
  const int i = blockIdx.x, t = threadIdx.x;
  const float* p = qb + (size_t)i * DMLP;
  float x[8]; float ss = 0.f;
  #pragma unroll
  for (int j = 0; j < 8; ++j){ x[j] = p[t + j * 256]; ss += x[j] * x[j]; }
  #pragma unroll
  for (int s = 32; s >= 1; s >>= 1) ss += __shfl_down(ss, s, 64);
  __shared__ float r4[4];
  if ((t & 63) == 0) r4[t >> 6] = ss;
  __syncthreads();
  const float tot = r4[0] + r4[1] + r4[2] + r4[3];
  const float inv = 1.0f / fmaxf(sqrtf(tot), 1e-12f);
  unsigned char* o = out + (size_t)i * DMLP;
  #pragma unroll
  for (int j = 0; j < 8; ++j){
    const int kx = t + j * 256;
    const int kk = kx & 63;
    const int pos = (kx & ~63) + ((kk >> 3) & 3) * 16 + (kk >> 5) * 8 + (kk & 7);
    o[pos] = f2f8(x[j] * inv);
  }
}

// ---------- top-5 insertion (sorted desc; strict > keeps earliest index on ties)
static __device__ __forceinline__ void tk_insert(float* v, int* ix, float nv, int ni){
  if (nv > v[4]){
    v[4] = nv; ix[4] = ni;
    #pragma unroll
    for (int j = 4; j > 0; --j){
      if (v[j] > v[j - 1]){
        float tv = v[j]; v[j] = v[j - 1]; v[j - 1] = tv;
        int   ti = ix[j]; ix[j] = ix[j - 1]; ix[j - 1] = ti;
      }
    }
  }
}

// ---------- GEMM1 (logits): 128x128 tile, ONE-SHOT K=128 stage (64KB LDS),
// single vmcnt(0)+barrier per block, then 4 k-slices with no further syncs.
// 1D grid + bijective XCD-chunk remap: each XCD gets 64 N-tiles x all 10
// M-tiles, so every B tile is fetched once per XCD (B HBM 128MB -> 16MB).
// Writes logits*INV_T, plus per-(row, 128-col-tile) lse partials (max, sumexp).
__global__ __launch_bounds__(256, 2) void gemm1_mfma(
    const unsigned short* __restrict__ A, const unsigned short* __restrict__ BT,
    float* __restrict__ outp, float* __restrict__ pm, float* __restrict__ ps){
  __shared__ __attribute__((aligned(16))) unsigned char smem[65536];
  unsigned short* At = (unsigned short*)smem;   // 4 slices x [128 rows][32 cols]
  unsigned short* Bt = At + 16384;              // same, 32KB each

  const int t    = threadIdx.x;
  const int lane = t & 63;
  const int wv   = t >> 6;        // wave 0..3, owns 32 rows x 128 cols
  const int lid  = lane & 15;
  const int quad = lane >> 4;
  // XCD-chunk remap (5120 % 8 == 0): bijective, M-tile fast within chunk
  const int h  = blockIdx.x;
  const int wg = (h & 7) * 640 + (h >> 3);
  const int bm = wg % 10;
  const int bn = wg / 10;
  const int m0 = bm * 128;
  const int n0 = bn * 128;

  f32x4 acc[2][8];
  #pragma unroll
  for (int mt = 0; mt < 2; ++mt)
    #pragma unroll
    for (int nt = 0; nt < 8; ++nt)
      acc[mt][nt] = f32x4{0.f, 0.f, 0.f, 0.f};

  const int arow = t >> 2;              // staging row (4 lanes x 16B = 64B/row)
  const int ace  = (t & 3) * 8;         // staging col (elements)

  // one-shot stage: 16 async loads/thread (A 8 + B 8), then a single seal
  #pragma unroll
  for (int kt = 0; kt < 4; ++kt)
    #pragma unroll
    for (int it = 0; it < 2; ++it){
      const int row = arow + it * 64;
      GLDS16(A + (size_t)(m0 + row) * DIM + kt * 32 + ace,
             At + kt * 4096 + (t + it * 256) * 8);
    }
  #pragma unroll
  for (int kt = 0; kt < 4; ++kt)
    #pragma unroll
    for (int it = 0; it < 2; ++it){
      const int row = arow + it * 64;
      GLDS16(BT + (size_t)(n0 + row) * DIM + kt * 32 + ace,
             Bt + kt * 4096 + (t + it * 256) * 8);
    }
  VMW(0);
  BAR();

  for (int kt = 0; kt < 4; ++kt){       // no syncs inside
    bf16x8 af[2], bfr[8];
    #pragma unroll
    for (int mt = 0; mt < 2; ++mt)
      af[mt] = *(const bf16x8*)(At + kt * 4096 + (wv * 32 + mt * 16 + lid) * 32 + quad * 8);
    #pragma unroll
    for (int nt = 0; nt < 8; ++nt)
      bfr[nt] = *(const bf16x8*)(Bt + kt * 4096 + (nt * 16 + lid) * 32 + quad * 8);
    #pragma unroll
    for (int mt = 0; mt < 2; ++mt)
      #pragma unroll
      for (int nt = 0; nt < 8; ++nt)
        acc[mt][nt] = __builtin_amdgcn_mfma_f32_16x16x32_bf16(af[mt], bfr[nt], acc[mt][nt], 0, 0, 0);
  }

  // C/D layout (m89-verified): col = lane&15, row = quad*4 + reg
  float mx[2][4], sm[2][4];
  #pragma unroll
  for (int mt = 0; mt < 2; ++mt)
    #pragma unroll
    for (int r = 0; r < 4; ++r) mx[mt][r] = -3.0e38f;
  #pragma unroll
  for (int mt = 0; mt < 2; ++mt)
    #pragma unroll
    for (int nt = 0; nt < 8; ++nt)
      #pragma unroll
      for (int r = 0; r < 4; ++r){
        const int mg = m0 + wv * 32 + mt * 16 + quad * 4 + r;
        const int ng = n0 + nt * 16 + lid;
        const float x = acc[mt][nt][r] * INV_T;
        outp[(size_t)mg * NCOLS + 1 + ng] = x;
        mx[mt][r] = fmaxf(mx[mt][r], x);
      }
  // 16-lane (lid) reduction: each quad owns its own 4 rows per mt
  #pragma unroll
  for (int mt = 0; mt < 2; ++mt)
    #pragma unroll
    for (int r = 0; r < 4; ++r){
      #pragma unroll
      for (int s = 8; s >= 1; s >>= 1)
        mx[mt][r] = fmaxf(mx[mt][r], __shfl_xor(mx[mt][r], s, 64));
      sm[mt][r] = 0.f;
    }
  #pragma unroll
  for (int mt = 0; mt < 2; ++mt)
    #pragma unroll
    for (int nt = 0; nt < 8; ++nt)
      #pragma unroll
      for (int r = 0; r < 4; ++r)
        sm[mt][r] += __expf(acc[mt][nt][r] * INV_T - mx[mt][r]);
  #pragma unroll
  for (int mt = 0; mt < 2; ++mt)
    #pragma unroll
    for (int r = 0; r < 4; ++r){
      #pragma unroll
      for (int s = 8; s >= 1; s >>= 1)
        sm[mt][r] += __shfl_xor(sm[mt][r], s, 64);
      if (lid == 0){
        const int mg = m0 + wv * 32 + mt * 16 + quad * 4 + r;
        pm[(size_t)mg * NBLK1 + bn] = mx[mt][r];
        ps[(size_t)mg * NBLK1 + bn] = sm[mt][r];
      }
    }
}

// ================== GEMM2 (fp8 e4m3): 256x128 tile, BK=64, 8 waves (4M x 2N),
// 3-buffer 2-ahead pipeline: stage kt+2 during kt; counted VMW(3) AFTER the
// MFMA segment (loads get ~1.7 iterations to land -> wait is normally free);
// one barrier per kt. 2 blocks/CU (72KB LDS, ~124 regs). Epilogue: acc dump to
// LDS scratch in 2 half-passes, serial row scans + full butterfly merge ->
// one 128-col chunk per block (NCHUNK=512, half the chunk-list traffic).

#define RDA8(SRC) do { _Pragma("unroll") for (int mf = 0; mf < 4; ++mf) \
    av[mf] = *(const longx2*)((SRC) + (wm * 64 + mf * 16 + lid) * 64 + qsw); } while(0)

#define RDB8(SRC) do { _Pragma("unroll") for (int nf = 0; nf < 4; ++nf) \
    bv[nf] = *(const longx2*)((SRC) + (wn * 64 + nf * 16 + lid) * 64 + qsw); } while(0)

#define MM_NF(nj_) do { \
    _Pragma("unroll") for (int mf = 0; mf < 4; ++mf){ \
      acc[mf][nj_] = __builtin_amdgcn_mfma_f32_16x16x32_fp8_fp8(av[mf].x, bv[nj_].x, acc[mf][nj_], 0, 0, 0); \
      acc[mf][nj_] = __builtin_amdgcn_mfma_f32_16x16x32_fp8_fp8(av[mf].y, bv[nj_].y, acc[mf][nj_], 0, 0, 0); } } while(0)

__global__ __launch_bounds__(512, 4) void gemm2_topk(
    const unsigned char* __restrict__ A, const unsigned char* __restrict__ BT,
    float* __restrict__ cval, int* __restrict__ cidx){
  // 3 buffers x (A 16KB + B 8KB) = 73728 B; epilogue scratch 128x133 f32 = 68096
  __shared__ __attribute__((aligned(16))) unsigned char smem[73728];

  const int t    = threadIdx.x;           // 0..511
  const int lane = t & 63;
  const int wv   = t >> 6;                // wave 0..7
  const int wm   = wv >> 1;               // 0..3 (64-row band)
  const int wn   = wv & 1;                // 0..1 (64-col band)
  const int lid  = lane & 15;
  const int quad = lane >> 4;
  const int qsw  = (quad ^ (lid & 3)) * 16;   // swizzled granule byte offset

  // T1: bijective XCD-chunked remap (2560 % 8 == 0)
  const int h  = blockIdx.x;
  const int wg = (h & 7) * 320 + (h >> 3);
  const int bm = wg % 5;                  // 5 M-tiles of 256 rows
  const int bn = wg / 5;                  // 512 N-tiles of 128 cols
  const int m0 = bm * 256;
  const int n0 = bn * 128;

  // staging source map (inverse swizzle; per-thread constant): granule p ->
  // row p>>2, stored pos p&3, source granule g = (p&3) ^ (row&3)
  const int srow = t >> 2;
  const size_t roff = (size_t)srow * DMLP + (size_t)(((t & 3) ^ (srow & 3)) * 16);
  const unsigned char* aB = A  + (size_t)m0 * DMLP;
  const unsigned char* bB = BT + (size_t)n0 * DMLP;

  f32x4 acc[4][4];
  #pragma unroll
  for (int a = 0; a < 4; ++a)
    #pragma unroll
    for (int b = 0; b < 4; ++b)
      acc[a][b] = f32x4{0.f, 0.f, 0.f, 0.f};

  longx2 av[4];    // A fragments, all 4 held (16 VGPR)
  longx2 bv[4];    // B fragments, all 4 held (16 VGPR)

  // STAGE(kt -> buffer bi): 3 async loads (A rows 0-127, A rows 128-255, B)
  #define STAGE2(kt_, bi_) do { \
    unsigned char* _a = smem + (bi_) * 24576; \
    const int _kc = (kt_) * 64; \
    GLDS16(aB + roff + _kc, _a + (size_t)t * 16); \
    GLDS16(aB + roff + 128 * DMLP + _kc, _a + (size_t)(512 + t) * 16); \
    GLDS16(bB + roff + _kc, _a + 16384 + (size_t)t * 16); } while(0)

  // prologue: 2 tiles in flight, seal tile 0
  STAGE2(0, 0);
  STAGE2(1, 1);
  VMW(3);               // kt0's 3 loads landed (kt1's 3 remain)
  BAR();

  for (int kt = 0; kt < NTK; ++kt){
    const int bi = kt % 3;
    unsigned char* curA = smem + bi * 24576;
    unsigned char* curB = curA + 16384;

    RDA8(curA);                         // 4 x ds_read_b128
    RDB8(curB);                         // 4 x ds_read_b128

    if (kt + 2 < NTK) STAGE2(kt + 2, (kt + 2) % 3);   // deep prefetch

    __builtin_amdgcn_s_setprio(1);
    MM_NF(0); MM_NF(1); MM_NF(2); MM_NF(3);
    __builtin_amdgcn_s_setprio(0);

    if (kt + 1 < NTK){
      if (kt + 2 < NTK){ VMW(3); } else { VMW(0); }   // kt+1's loads landed
      BAR();                            // seal: all waves may read buf[kt+1]
    }
  }

  // ---- fused top-5 via LDS scratch, 2 half-passes of 128 rows ----
  float* scratch = (float*)smem;        // [128][133] f32
  BAR();                                // all reads of K-loop buffers done
  #pragma unroll
  for (int p = 0; p < 2; ++p){
    if ((wm >> 1) == p){                // waves owning rows p*128..p*128+127
      #pragma unroll
      for (int mf = 0; mf < 4; ++mf)
        #pragma unroll
        for (int nf = 0; nf < 4; ++nf)
          #pragma unroll
          for (int r = 0; r < 4; ++r){
            const int lr = (wm & 1) * 64 + mf * 16 + quad * 4 + r;
            scratch[lr * 133 + wn * 64 + nf * 16 + lid] = acc[mf][nf][r];
          }
    }
    __syncthreads();
    {
      const int lr  = t >> 2;           // 0..127
      const int seg = t & 3;            // 4 threads/row, 32 cols each
      float v[5]; int ix[5];
      #pragma unroll
      for (int j = 0; j < 5; ++j){ v[j] = -3.0e38f; ix[j] = 0; }
      const int cb0 = seg * 32;
      for (int j = 0; j < 32; ++j)
        tk_insert(v, ix, scratch[lr * 133 + cb0 + j], n0 + cb0 + j);
      #pragma unroll
      for (int s = 1; s <= 2; s <<= 1){ // full butterfly: all segs end complete
        float pv[5]; int pi[5];
        #pragma unroll
        for (int j = 0; j < 5; ++j){ pv[j] = __shfl_xor(v[j], s, 64); pi[j] = __shfl_xor(ix[j], s, 64); }
        #pragma unroll
        for (int j = 0; j < 5; ++j) tk_insert(v, ix, pv[j], pi[j]);
      }
      if (seg == 0){
        const int rowg = m0 + p * 128 + lr;
        const size_t cb = ((size_t)rowg * NCHUNK + bn) * NTOPK;
        #pragma unroll
        for (int j = 0; j < 5; ++j){ cval[cb + j] = v[j]; cidx[cb + j] = ix[j]; }
      }
    }
    __syncthreads();                    // before next pass overwrites scratch
  }
}

// ---------- merge 512 chunk top-5 lists per row -> global top-5 indices
__global__ __launch_bounds__(256) void topk_merge(
    const float* __restrict__ cval, const int* __restrict__ cidx, int* __restrict__ knn){
  const int row = blockIdx.x, t = threadIdx.x;
  float v[5]; int ix[5];
  #pragma unroll
  for (int j = 0; j < 5; ++j){ v[j] = -3.0e38f; ix[j] = 0; }
  const size_t base = (size_t)row * (NCHUNK * NTOPK);
  #pragma unroll
  for (int j = 0; j < 10; ++j){                  // 2560 candidates / 256 threads
    const int c = t * 10 + j;
    tk_insert(v, ix, cval[base + c], cidx[base + c]);
  }
  __shared__ float lv[256 * 5];
  __shared__ int   li[256 * 5];
  #pragma unroll
  for (int j = 0; j < 5; ++j){ lv[t * 5 + j] = v[j]; li[t * 5 + j] = ix[j]; }
  __syncthreads();
  if (t < 64){
    float v2[5]; int ix2[5];
    #pragma unroll
    for (int j = 0; j < 5; ++j){ v2[j] = -3.0e38f; ix2[j] = 0; }
    for (int L = 0; L < 4; ++L)
      #pragma unroll
      for (int j = 0; j < 5; ++j)
        tk_insert(v2, ix2, lv[(t * 4 + L) * 5 + j], li[(t * 4 + L) * 5 + j]);
    #pragma unroll
    for (int s = 32; s >= 1; s >>= 1){           // tree merge; lane 0 ends valid
      float pv[5]; int pi[5];
      #pragma unroll
      for (int j = 0; j < 5; ++j){ pv[j] = __shfl_down(v2[j], s, 64); pi[j] = __shfl_down(ix2[j], s, 64); }
      #pragma unroll
      for (int j = 0; j < 5; ++j) tk_insert(v2, ix2, pv[j], pi[j]);
    }
    if (t == 0){
      #pragma unroll
      for (int j = 0; j < 5; ++j) knn[(size_t)row * NTOPK + j] = ix2[j];
    }
  }
}

// ---------- merge per-tile lse partials -> per-row logsumexp
__global__ __launch_bounds__(256) void lse_merge(
    const float* __restrict__ pm, const float* __restrict__ ps,
    float* __restrict__ lse){
  const int row = blockIdx.x, t = threadIdx.x;
  const float* pmr = pm + (size_t)row * NBLK1;
  const float* psr = ps + (size_t)row * NBLK1;
  float m = -1.0e30f, s = 0.f;
  #pragma unroll
  for (int c = 0; c < 2; ++c){               // 512 partials / 256 threads
    const float om = pmr[t + c * 256], os = psr[t + c * 256];
    const float nm = fmaxf(m, om);
    s = s * __expf(m - nm) + os * __expf(om - nm);
    m = nm;
  }
  #pragma unroll
  for (int sh = 32; sh >= 1; sh >>= 1){
    const float om = __shfl_down(m, sh, 64), os = __shfl_down(s, sh, 64);
    const float nm = fmaxf(m, om);
    s = s * __expf(m - nm) + os * __expf(om - nm);
    m = nm;
  }
  __shared__ float sm2[4], ss2[4];
  if ((t & 63) == 0){ sm2[t >> 6] = m; ss2[t >> 6] = s; }
  __syncthreads();
  if (t == 0){
    float M = sm2[0], S = ss2[0];
    #pragma unroll
    for (int w = 1; w < 4; ++w){
      const float nm = fmaxf(M, sm2[w]);
      S = S * __expf(M - nm) + ss2[w] * __expf(sm2[w] - nm);
      M = nm;
    }
    lse[row] = M + __logf(S);
  }
}

// ---------- loss = mean over 6400 of (lse[row] - logit[row][1+idx])
__global__ __launch_bounds__(256) void loss_kernel(
    const float* __restrict__ logits, const float* __restrict__ lse,
    const int* __restrict__ knn, float* __restrict__ loss){
  const int i = blockIdx.x * 256 + threadIdx.x;
  float c = 0.f;
  if (i < M_){
    const float l = lse[i];
    #pragma unroll
    for (int j = 0; j < 5; ++j){
      const int id = knn[(size_t)i * NTOPK + j];
      c += l - logits[(size_t)i * NCOLS + 1 + id];
    }
    c *= (1.0f / 6400.0f);
  }
  #pragma unroll
  for (int s = 32; s >= 1; s >>= 1) c += __shfl_down(c, s, 64);
  if ((threadIdx.x & 63) == 0) atomicAdd(loss, c);
}

extern "C" void kernel_launch(void* const* d_in, const int* in_sizes, int n_in,
                              void* d_out, int out_size, void* d_ws, size_t ws_size,
                              hipStream_t stream){
  const float* q   = (const float*)d_in[0];   // [256,5,128]
  const float* k   = (const float*)d_in[1];   // [256,128]
  const float* qbI = (const float*)d_in[2];   // [256,5,2048]
  const float* que = (const float*)d_in[3];   // [128,65536]
  const float* qbb = (const float*)d_in[4];   // [2048,65536]
  float* out = (float*)d_out;

  unsigned char* w = (unsigned char*)d_ws;
  unsigned short* qn    = (unsigned short*)w; w += (size_t)M_ * DIM  * 2;   // 320 KB
  unsigned char*  qbn8  = (unsigned char*)w;  w += (size_t)M_ * DMLP;      // 2.5 MB
  unsigned short* queT  = (unsigned short*)w; w += (size_t)KQ * DIM  * 2;   // 16 MB
  unsigned char*  qbbT8 = (unsigned char*)w;  w += (size_t)KQ * DMLP;      // 128 MB
  float* cval = (float*)w;                    w += (size_t)M_ * NCHUNK * NTOPK * 4;  // 13 MB
  int*   cidx = (int*)w;                      w += (size_t)M_ * NCHUNK * NTOPK * 4;  // 13 MB
  int*   knn  = (int*)w;                      w += (size_t)M_ * NTOPK * 4;
  float* lseb = (float*)w;                    w += (size_t)M_ * 4;
  float* pm   = (float*)w;                    w += (size_t)M_ * NBLK1 * 4;  // 2.6 MB
  float* ps   = (float*)w;                    w += (size_t)M_ * NBLK1 * 4;  // 2.6 MB

  // labels (1280 int32 zeros) + loss slot, contiguous after logits
  hipMemsetAsync(out + (size_t)M_ * NCOLS, 0, (M_ + 1) * sizeof(float), stream);

  transpose_bf16<<<dim3(KQ / 64, DIM  / 64), 256, 0, stream>>>(que, queT, DIM, KQ);
  transpose_fp8 <<<dim3(KQ / 64, DMLP / 64), 256, 0, stream>>>(qbb, qbbT8, DMLP, KQ);
  normq_kernel <<<M_, 128, 0, stream>>>(q, k, qn, out);
  normqb_kernel<<<M_, 256, 0, stream>>>(qbI, qbn8);
  // GEMM1: one-shot K stage, 1D grid, XCD-chunked (B read once per XCD)
  gemm1_mfma<<<dim3(5120), 256, 0, stream>>>(qn, queT, out, pm, ps);
  // GEMM2: fp8 256x128, 3-buffer 2-ahead pipeline, 2 blocks/CU, XCD-chunked
  gemm2_topk<<<dim3(2560), 512, 0, stream>>>(qbn8, qbbT8, cval, cidx);
  topk_merge<<<M_, 256, 0, stream>>>(cval, cidx, knn);
  lse_merge<<<M_, 256, 0, stream>>>(pm, ps, lseb);
  loss_kernel<<<(M_ + 255) / 256, 256, 0, stream>>>(out, lseb, knn,
                                                    out + (size_t)M_ * NCOLS + M_);
}